// Round 1
// 389.028 us; speedup vs baseline: 1.0816x; 1.0816x over previous
//
#include <hip/hip_runtime.h>

typedef __bf16 bf16;
typedef __bf16 bf16x8 __attribute__((ext_vector_type(8)));
typedef float f32x4 __attribute__((ext_vector_type(4)));

#define D_MODEL 2048
#define SEQ 2048
#define NH 16
#define HEAD_DIM 128
#define NBATCH 2
#define SM_SCALE 0.08838834764831845f  // 1/sqrt(128)
#define WSEG 4194304                   // 2048*2048
#define NT_TILES 32                    // K / 64

typedef __attribute__((address_space(1))) const void* gas_cp;
typedef __attribute__((address_space(3))) void* las_p;
__device__ __forceinline__ void ll16(const bf16* g, bf16* l) {
  // async global->LDS, 16B/lane; LDS dest = wave-uniform base + lane*16
  __builtin_amdgcn_global_load_lds((gas_cp)g, (las_p)l, 16, 0, 0);
}

// ---------------------------------------------------------------------------
// fp32 -> bf16 converters (one-shot, pure BW)
// ---------------------------------------------------------------------------
__device__ __forceinline__ bf16x8 cvt8(const float* p) {
  float4 a = *(const float4*)p;
  float4 b = *(const float4*)(p + 4);
  bf16x8 v;
  v[0] = (bf16)a.x; v[1] = (bf16)a.y; v[2] = (bf16)a.z; v[3] = (bf16)a.w;
  v[4] = (bf16)b.x; v[5] = (bf16)b.y; v[6] = (bf16)b.z; v[7] = (bf16)b.w;
  return v;
}

__global__ __launch_bounds__(256)
void cvt_hidden(const float* __restrict__ src, bf16* __restrict__ dst) {
  size_t i = ((size_t)blockIdx.x * 256 + threadIdx.x) * 8;
  *(bf16x8*)(dst + i) = cvt8(src + i);
}

__global__ __launch_bounds__(256)
void cvt_weights(const float* __restrict__ w0, const float* __restrict__ w1,
                 const float* __restrict__ w2, const float* __restrict__ w3,
                 bf16* __restrict__ dst) {
  const float* src = (blockIdx.y == 0) ? w0 : (blockIdx.y == 1) ? w1
                   : (blockIdx.y == 2) ? w2 : w3;
  size_t i = ((size_t)blockIdx.x * 256 + threadIdx.x) * 8;
  *(bf16x8*)(dst + (size_t)blockIdx.y * WSEG + i) = cvt8(src + i);
}

// ---------------------------------------------------------------------------
// 256x256-tile, 8-wave, 4-phase-per-K-tile GEMM (HK/m201 schedule in plain
// HIP). BK=64. Per phase: one C-quadrant (A-half x B-half) x K=64 = 16 MFMA,
// one half-tile prefetch (2 global_load_lds/thread), raw s_barrier pairs,
// counted vmcnt(4) once per K-tile (never 0 in the main loop), setprio(1)
// around the MFMA cluster.
//
// LDS 128KiB: [buf][A h0|A h1|B h0|B h1] x 16KiB halves (128 rows x 64 k).
// XOR swizzle q ^= (row&7)<<4 applied via inverse-swizzled per-lane GLOBAL
// source (gload_lds dest stays linear) + swizzled ds_read address -> the
// stride-128B fragment reads go from 16-way to 2-way (free) bank aliasing.
//
// Quadrant order (0,0),(1,0),(1,1),(0,1): per-phase new ds_reads 12/4/8/4,
// and each half's last reader finishes early enough that same-buffer
// prefetch of tile t+2 at P2 (B h0) / P3 (A h1) is race-free; other-buffer
// halves of tile t+1 staged at P0 (A h0) / P1 (B h1).  At the tile boundary
// vmcnt(4) leaves exactly those two t+2 halves in flight.
//
// Wave mapping: wr=w>>1 picks 32 rows/quadrant, wc=w&1 picks cols
// {wc*32+0,16, 64+wc*32+0,16} so RoPE pairs (c,c+64) = (ni, ni+2) stay
// register-local. MODE 0: plain float store. MODE 1: fused QKV epilogue
// (Q/K RoPE, V scatter-transpose), nBase>>11 selects the matrix.
// ---------------------------------------------------------------------------
#define LOADA(HB)                                                            \
  _Pragma("unroll") for (int mi = 0; mi < 2; mi++)                           \
  _Pragma("unroll") for (int ks = 0; ks < 2; ks++)                           \
      af[mi][ks] = *(const bf16x8*)((HB) + ((rowA + mi * 16) << 7) +         \
                                    (ks ? kx1 : kx0));

#define LOADB(HB)                                                            \
  _Pragma("unroll") for (int ks = 0; ks < 2; ks++) {                         \
    bfr[0][ks] = *(const bf16x8*)((HB) + (rb0 << 7) + (ks ? kx1 : kx0));     \
    bfr[1][ks] = *(const bf16x8*)((HB) + (rb1 << 7) + (ks ? kx1 : kx0));     \
    bfr[2][ks] = *(const bf16x8*)((HB) + (rb2 << 7) + (ks ? kx1 : kx0));     \
    bfr[3][ks] = *(const bf16x8*)((HB) + (rb3 << 7) + (ks ? kx1 : kx0));     \
  }

#define MMAC(QM, QN)                                                         \
  _Pragma("unroll") for (int ks = 0; ks < 2; ks++)                           \
  _Pragma("unroll") for (int mi = 0; mi < 2; mi++)                           \
  _Pragma("unroll") for (int ni = 0; ni < 4; ni++)                           \
      acc[QM][QN][mi][ni] = __builtin_amdgcn_mfma_f32_16x16x32_bf16(         \
          af[mi][ks], bfr[ni][ks], acc[QM][QN][mi][ni], 0, 0, 0);

// stage one 128x64 half-tile: 2 gload_lds/thread, linear LDS dest,
// inverse-swizzled global k-offset (kelem) so swizzled reads see logical data
#define STAGE(GP, ROW0, KT, LB)                                              \
  _Pragma("unroll") for (int i_ = 0; i_ < 2; i_++) {                         \
    ll16((GP) + (size_t)((ROW0) + (i_ * 8 + w) * 8 + l8) * D_MODEL +         \
             (KT) * 64 + kelem,                                              \
         (bf16*)((LB) + (i_ * 8 + w) * 1024));                               \
  }

#define PHASE_SYNC_PRE()                                                     \
  __builtin_amdgcn_s_barrier();                                              \
  asm volatile("s_waitcnt lgkmcnt(0)" ::: "memory");                         \
  __builtin_amdgcn_sched_barrier(0);                                         \
  __builtin_amdgcn_s_setprio(1);

#define PHASE_SYNC_POST()                                                    \
  __builtin_amdgcn_s_setprio(0);                                             \
  __builtin_amdgcn_s_barrier();

template <typename TC, int MODE, int NBN>
__global__ __launch_bounds__(512, 2)
void gemm8p(const bf16* __restrict__ A, const bf16* __restrict__ W,
            TC* __restrict__ C, bf16* __restrict__ Qo, bf16* __restrict__ Ko,
            bf16* __restrict__ Vo, const int* __restrict__ pos_ids) {
  __shared__ __align__(16) char smem[131072];

  const int tid  = threadIdx.x;
  const int lane = tid & 63;
  const int w    = tid >> 6;           // 0..7
  const int quad = lane >> 4, l15 = lane & 15;
  const int wr   = w >> 1;             // 0..3: 32-row strip in quadrant
  const int wc   = w & 1;              // 0..1: col pick
  const int l8   = lane >> 3, l7 = lane & 7;
  const int kelem = 8 * (l7 ^ l8);     // inverse-swizzle of global source

  // XCD-bijective swizzle (grid % 8 == 0 for both uses)
  const int nwg = 16 * NBN;
  const int bid = blockIdx.x;
  const int lin = (bid & 7) * (nwg >> 3) + (bid >> 3);
  const int by = lin / NBN, bx = lin % NBN;
  const int mBase = by << 8, nBase = bx << 8;

  // read-side swizzled k offsets: q = (row<<7) + ((ks*64 + quad*16) ^ ((row&7)<<4))
  const int kx0 = (quad * 16) ^ ((l15 & 7) << 4);
  const int kx1 = kx0 ^ 64;
  const int rowA = wr * 32 + l15;
  const int rb0 = wc * 32 + l15, rb1 = rb0 + 16, rb2 = rb0 + 64, rb3 = rb0 + 80;

  f32x4 acc[2][2][2][4];
#pragma unroll
  for (int a = 0; a < 2; a++)
#pragma unroll
    for (int b = 0; b < 2; b++)
#pragma unroll
      for (int c = 0; c < 2; c++)
#pragma unroll
        for (int d = 0; d < 4; d++) acc[a][b][c][d] = 0.0f;

  bf16x8 af[2][2], bfr[4][2];

  // prologue: tile0 all 4 halves + tile1's same-slot halves (B h0, A h1)
  {
    char* s = smem;
    STAGE(A, mBase,       0, s + 0);              // A h0 t0
    STAGE(A, mBase + 128, 0, s + 16384);          // A h1 t0
    STAGE(W, nBase,       0, s + 32768);          // B h0 t0
    STAGE(W, nBase + 128, 0, s + 49152);          // B h1 t0
    STAGE(W, nBase,       1, s + 65536 + 32768);  // B h0 t1
    STAGE(A, mBase + 128, 1, s + 65536 + 16384);  // A h1 t1
  }
  asm volatile("s_waitcnt vmcnt(4)" ::: "memory");  // tile0 fully arrived
  __builtin_amdgcn_s_barrier();

  for (int t = 0; t < NT_TILES; ++t) {
    const int buf = t & 1;
    char* const A0  = smem + buf * 65536;
    char* const A1h = A0 + 16384;
    char* const B0  = A0 + 32768;
    char* const B1h = B0 + 16384;
    char* const oA0 = smem + (buf ^ 1) * 65536;
    char* const oB1 = oA0 + 32768 + 16384;

    // ---- P0: quadrant (0,0); stage A h0 (t+1) -> other buf ----
    LOADA(A0);
    LOADB(B0);
    if (t + 1 < NT_TILES) STAGE(A, mBase, t + 1, oA0);
    PHASE_SYNC_PRE();
    MMAC(0, 0);
    PHASE_SYNC_POST();

    // ---- P1: quadrant (1,0); stage B h1 (t+1) -> other buf ----
    LOADA(A1h);
    if (t + 1 < NT_TILES) STAGE(W, nBase + 128, t + 1, oB1);
    PHASE_SYNC_PRE();
    MMAC(1, 0);
    PHASE_SYNC_POST();

    // ---- P2: quadrant (1,1); stage B h0 (t+2) -> SAME buf (B h0 dead) ----
    LOADB(B1h);
    if (t + 2 < NT_TILES) STAGE(W, nBase, t + 2, B0);
    PHASE_SYNC_PRE();
    MMAC(1, 1);
    PHASE_SYNC_POST();

    // ---- P3: quadrant (0,1); stage A h1 (t+2) -> SAME buf (A h1 dead) ----
    LOADA(A0);
    if (t + 2 < NT_TILES) STAGE(A, mBase + 128, t + 2, A1h);
    __builtin_amdgcn_s_barrier();
    asm volatile("s_waitcnt lgkmcnt(0)" ::: "memory");
    __builtin_amdgcn_sched_barrier(0);
    __builtin_amdgcn_s_setprio(1);
    MMAC(0, 1);
    __builtin_amdgcn_s_setprio(0);
    if (t + 2 < NT_TILES)
      asm volatile("s_waitcnt vmcnt(4)" ::: "memory");  // tile t+1 complete
    else
      asm volatile("s_waitcnt vmcnt(0)" ::: "memory");  // epilogue drain
    __builtin_amdgcn_s_barrier();
  }

  // C/D layout (verified): col = lane&15, row = quad*4 + reg
  // m = mBase + qm*128 + wr*32 + mi*16 + quad*4 + r
  // n = nBase + qn*128 + wc*32 + (ni&1)*16 + (ni>>1)*64 + l15
  if (MODE == 0) {
#pragma unroll
    for (int qm = 0; qm < 2; qm++)
#pragma unroll
      for (int qn = 0; qn < 2; qn++)
#pragma unroll
        for (int mi = 0; mi < 2; mi++)
#pragma unroll
          for (int ni = 0; ni < 4; ni++) {
            int n = nBase + qn * 128 + wc * 32 + (ni & 1) * 16 + (ni >> 1) * 64 + l15;
            int mb = mBase + qm * 128 + wr * 32 + mi * 16 + quad * 4;
            TC* cp = C + (size_t)mb * D_MODEL + n;
#pragma unroll
            for (int r = 0; r < 4; r++) cp[(size_t)r * D_MODEL] = (TC)acc[qm][qn][mi][ni][r];
          }
  } else {
    const int matrix = nBase >> 11;  // 0=Q 1=K 2=V
    const int nb     = nBase & 2047; // within-matrix col base (head-aligned)
    if (matrix == 2) {
#pragma unroll
      for (int qm = 0; qm < 2; qm++)
#pragma unroll
        for (int qn = 0; qn < 2; qn++) {
          const int h = (nb >> 7) + qn;
#pragma unroll
          for (int mi = 0; mi < 2; mi++)
#pragma unroll
            for (int ni = 0; ni < 4; ni++) {
              const int hd = wc * 32 + (ni & 1) * 16 + (ni >> 1) * 64 + l15;
#pragma unroll
              for (int r = 0; r < 4; r++) {
                int m = mBase + qm * 128 + wr * 32 + mi * 16 + quad * 4 + r;
                int b = m >> 11, s2 = m & 2047;
                Vo[((size_t)((b * NH + h) * HEAD_DIM + hd)) * SEQ + s2] =
                    (bf16)acc[qm][qn][mi][ni][r];
              }
            }
        }
    } else {
      bf16* Out = (matrix == 0) ? Qo : Ko;
      float invf[2];
#pragma unroll
      for (int ni = 0; ni < 2; ni++)
        invf[ni] = __expf(-(float)(wc * 32 + ni * 16 + l15) *
                          (9.210340371976184f / 64.0f));
#pragma unroll
      for (int qm = 0; qm < 2; qm++)
#pragma unroll
        for (int mi = 0; mi < 2; mi++)
#pragma unroll
          for (int r = 0; r < 4; r++) {
            int m = mBase + qm * 128 + wr * 32 + mi * 16 + quad * 4 + r;
            float pos = (float)pos_ids[m];
#pragma unroll
            for (int qn = 0; qn < 2; qn++) {
              bf16* op = Out + (size_t)m * D_MODEL + nb + qn * 128 + wc * 32 + l15;
#pragma unroll
              for (int ni = 0; ni < 2; ni++) {
                float sn, cs;
                __sincosf(pos * invf[ni], &sn, &cs);
                float q0 = acc[qm][qn][mi][ni][r];
                float q1 = acc[qm][qn][mi][ni + 2][r];
                op[ni * 16]      = (bf16)(q0 * cs - q1 * sn);
                op[ni * 16 + 64] = (bf16)(q1 * cs + q0 * sn);
              }
            }
          }
    }
  }
}

// ---------------------------------------------------------------------------
// MFMA flash attention, causal (unchanged this round). One 64-row q-subtile
// per block (4 waves x 16 rows); grid (bh=32, 32) with s = 31 - blockIdx.y.
// ---------------------------------------------------------------------------
__global__ __launch_bounds__(256, 3)
void attn_mfma(const bf16* __restrict__ Q, const bf16* __restrict__ K,
               const bf16* __restrict__ Vt, bf16* __restrict__ O) {
  __shared__ __align__(16) bf16 K_lds[64 * 136];   // [t][hd], pad 128->136
  __shared__ __align__(16) bf16 V_lds[128 * 72];   // [d][t],  pad 64->72
  __shared__ __align__(16) bf16 P_lds[64 * 72];    // wave-local 16 rows each

  const int tid  = threadIdx.x;
  const int lane = tid & 63;
  const int w    = tid >> 6;
  const int quad = lane >> 4, l15 = lane & 15;
  const int s    = 31 - blockIdx.y;   // subtile index, heavy first
  const int bh   = blockIdx.x;        // b*NH + h
  const size_t qkBase = (size_t)(bh >> 4) * SEQ * D_MODEL + (size_t)(bh & 15) * HEAD_DIM;
  const size_t vBase  = (size_t)bh * HEAD_DIM * SEQ;

  const int qbase = s * 64 + w * 16;  // wave's 16 q-rows

  bf16x8 qa[4];
#pragma unroll
  for (int kk = 0; kk < 4; kk++)
    qa[kk] = *(const bf16x8*)(Q + qkBase + (size_t)(qbase + l15) * D_MODEL + kk * 32 + quad * 8);

  bf16x8 ones;
#pragma unroll
  for (int i = 0; i < 8; i++) ones[i] = (bf16)1.0f;

  f32x4 oacc[8], ls;
#pragma unroll
  for (int ni = 0; ni < 8; ni++) oacc[ni] = 0.0f;
  ls = 0.0f;

  const int ntiles = s + 1;

  bf16x8 kr[4], vr[4];
  auto loadKV = [&](int t0) {
#pragma unroll
    for (int i = 0; i < 4; i++) {
      int c = tid + 256 * i;
      kr[i] = *(const bf16x8*)(K + qkBase + (size_t)(t0 + (c >> 4)) * D_MODEL + (c & 15) * 8);
    }
#pragma unroll
    for (int i = 0; i < 4; i++) {
      int c = tid + 256 * i;
      vr[i] = *(const bf16x8*)(Vt + vBase + (size_t)(c >> 3) * SEQ + t0 + (c & 7) * 8);
    }
  };
  loadKV(0);

  const int prow = w * 16;  // wave-local P rows

  for (int tt = 0; tt < ntiles; tt++) {
    const int t0 = tt * 64;
    __syncthreads();
#pragma unroll
    for (int i = 0; i < 4; i++) {
      int c = tid + 256 * i;
      *(bf16x8*)&K_lds[(c >> 4) * 136 + (c & 15) * 8] = kr[i];
    }
#pragma unroll
    for (int i = 0; i < 4; i++) {
      int c = tid + 256 * i;
      *(bf16x8*)&V_lds[(c >> 3) * 72 + (c & 7) * 8] = vr[i];
    }
    __syncthreads();
    if (tt + 1 < ntiles) loadKV(t0 + 64);

    // --- S = Q K^T ---
    f32x4 sacc[4];
#pragma unroll
    for (int ni = 0; ni < 4; ni++) sacc[ni] = 0.0f;
#pragma unroll
    for (int kk = 0; kk < 4; kk++) {
#pragma unroll
      for (int ni = 0; ni < 4; ni++) {
        bf16x8 kf = *(const bf16x8*)&K_lds[(ni * 16 + l15) * 136 + kk * 32 + quad * 8];
        sacc[ni] = __builtin_amdgcn_mfma_f32_16x16x32_bf16(qa[kk], kf, sacc[ni], 0, 0, 0);
      }
    }

    // --- exp (+mask on diagonal tile only) -> P_lds ---
    if (tt == s) {
#pragma unroll
      for (int r = 0; r < 4; r++) {
        int qrow = qbase + quad * 4 + r;
#pragma unroll
        for (int ni = 0; ni < 4; ni++) {
          int tcol = t0 + ni * 16 + l15;
          float pv = (tcol <= qrow) ? __expf(fminf(sacc[ni][r] * SM_SCALE, 30.0f)) : 0.0f;
          P_lds[(prow + quad * 4 + r) * 72 + ni * 16 + l15] = (bf16)pv;
        }
      }
    } else {
#pragma unroll
      for (int r = 0; r < 4; r++)
#pragma unroll
        for (int ni = 0; ni < 4; ni++)
          P_lds[(prow + quad * 4 + r) * 72 + ni * 16 + l15] =
              (bf16)__expf(fminf(sacc[ni][r] * SM_SCALE, 30.0f));
    }

    // --- O += P V; row-sum via ones-vector MFMA ---
#pragma unroll
    for (int kk2 = 0; kk2 < 2; kk2++) {
      bf16x8 pf = *(const bf16x8*)&P_lds[(prow + l15) * 72 + kk2 * 32 + quad * 8];
#pragma unroll
      for (int ni = 0; ni < 8; ni++) {
        bf16x8 vf = *(const bf16x8*)&V_lds[(ni * 16 + l15) * 72 + kk2 * 32 + quad * 8];
        oacc[ni] = __builtin_amdgcn_mfma_f32_16x16x32_bf16(pf, vf, oacc[ni], 0, 0, 0);
      }
      ls = __builtin_amdgcn_mfma_f32_16x16x32_bf16(pf, ones, ls, 0, 0, 0);
    }
  }

  // epilogue
#pragma unroll
  for (int r = 0; r < 4; r++) {
    float inv = 1.0f / ls[r];
    bf16* op = O + qkBase + (size_t)(qbase + quad * 4 + r) * D_MODEL;
#pragma unroll
    for (int ni = 0; ni < 8; ni++)
      op[ni * 16 + l15] = (bf16)(oacc[ni][r] * inv);
  }
}

extern "C" void kernel_launch(void* const* d_in, const int* in_sizes, int n_in,
                              void* d_out, int out_size, void* d_ws, size_t ws_size,
                              hipStream_t stream) {
  const float* hidden = (const float*)d_in[0];
  // d_in[1] = attention_mask (causal -1e9): applied analytically in attn_mfma
  const int* pos = (const int*)d_in[2];
  const float* Wq = (const float*)d_in[3];
  const float* Wk = (const float*)d_in[4];
  const float* Wv = (const float*)d_in[5];
  const float* Wo = (const float*)d_in[6];
  float* out = (float*)d_out;

  const size_t TENS = (size_t)NBATCH * SEQ * D_MODEL;  // 8,388,608
  bf16* Qb = (bf16*)d_ws;
  bf16* Kb = Qb + TENS;
  bf16* Vt = Kb + TENS;      // [B,H,HD,S]
  bf16* AO = Vt + TENS;      // attention out [B,S,D]
  bf16* Hb = AO + TENS;      // bf16 hidden
  bf16* Wb = Hb + TENS;      // [Wq;Wk;Wv;Wo] bf16, fused N=6144 rows

  cvt_hidden<<<dim3(TENS / 2048), dim3(256), 0, stream>>>(hidden, Hb);
  cvt_weights<<<dim3(WSEG / 2048, 4), dim3(256), 0, stream>>>(Wq, Wk, Wv, Wo, Wb);

  // fused QKV projection + RoPE + V-transpose: M=4096, N=6144 -> 16x24 blocks
  gemm8p<bf16, 1, 24><<<dim3(384), dim3(512), 0, stream>>>(
      Hb, Wb, (bf16*)nullptr, Qb, Kb, Vt, pos);

  attn_mfma<<<dim3(NBATCH * NH, 32), dim3(256), 0, stream>>>(Qb, Kb, Vt, AO);

  // final projection: M=4096, N=2048 -> 16x8 blocks
  gemm8p<float, 0, 8><<<dim3(128), dim3(512), 0, stream>>>(
      AO, Wb + 3 * (size_t)WSEG, out, nullptr, nullptr, nullptr, nullptr);
}

// Round 2
// 376.762 us; speedup vs baseline: 1.1169x; 1.0326x over previous
//
#include <hip/hip_runtime.h>

typedef __bf16 bf16;
typedef __bf16 bf16x8 __attribute__((ext_vector_type(8)));
typedef float f32x4 __attribute__((ext_vector_type(4)));

#define D_MODEL 2048
#define SEQ 2048
#define NH 16
#define HEAD_DIM 128
#define NBATCH 2
#define SM_SCALE 0.08838834764831845f  // 1/sqrt(128)
#define WSEG 4194304                   // 2048*2048
#define NT_TILES 32                    // K / 64

typedef __attribute__((address_space(1))) const void* gas_cp;
typedef __attribute__((address_space(3))) void* las_p;
__device__ __forceinline__ void ll16(const bf16* g, bf16* l) {
  // async global->LDS, 16B/lane; LDS dest = wave-uniform base + lane*16
  __builtin_amdgcn_global_load_lds((gas_cp)g, (las_p)l, 16, 0, 0);
}

// ---------------------------------------------------------------------------
// fp32 -> bf16 converters (one-shot, pure BW)
// ---------------------------------------------------------------------------
__device__ __forceinline__ bf16x8 cvt8(const float* p) {
  float4 a = *(const float4*)p;
  float4 b = *(const float4*)(p + 4);
  bf16x8 v;
  v[0] = (bf16)a.x; v[1] = (bf16)a.y; v[2] = (bf16)a.z; v[3] = (bf16)a.w;
  v[4] = (bf16)b.x; v[5] = (bf16)b.y; v[6] = (bf16)b.z; v[7] = (bf16)b.w;
  return v;
}

__global__ __launch_bounds__(256)
void cvt_hidden(const float* __restrict__ src, bf16* __restrict__ dst) {
  size_t i = ((size_t)blockIdx.x * 256 + threadIdx.x) * 8;
  *(bf16x8*)(dst + i) = cvt8(src + i);
}

__global__ __launch_bounds__(256)
void cvt_weights(const float* __restrict__ w0, const float* __restrict__ w1,
                 const float* __restrict__ w2, const float* __restrict__ w3,
                 bf16* __restrict__ dst) {
  const float* src = (blockIdx.y == 0) ? w0 : (blockIdx.y == 1) ? w1
                   : (blockIdx.y == 2) ? w2 : w3;
  size_t i = ((size_t)blockIdx.x * 256 + threadIdx.x) * 8;
  *(bf16x8*)(dst + (size_t)blockIdx.y * WSEG + i) = cvt8(src + i);
}

// ---------------------------------------------------------------------------
// 256x256-tile, 8-wave, 4-phase-per-K-tile GEMM (QKV). Same schedule as R1,
// with one change: A fragments for both quadrants are HELD across the K-tile
// (afA loaded at P0, afB at P1; P2 reuses afB, P3 reuses afA). This removes
// P3's 4-read re-load: 28 -> 24 ds_read_b128 per K-tile per wave (= m201's
// ratio). Region-death ordering unchanged: A-h0 last read at P0, A-h1 at P1,
// so same-buffer prefetch at P2/P3 stays race-free.
// ---------------------------------------------------------------------------
#define LOADA(HB, AF)                                                        \
  _Pragma("unroll") for (int mi = 0; mi < 2; mi++)                           \
  _Pragma("unroll") for (int ks = 0; ks < 2; ks++)                           \
      AF[mi][ks] = *(const bf16x8*)((HB) + ((rowA + mi * 16) << 7) +         \
                                    (ks ? kx1 : kx0));

#define LOADB(HB)                                                            \
  _Pragma("unroll") for (int ks = 0; ks < 2; ks++) {                         \
    bfr[0][ks] = *(const bf16x8*)((HB) + (rb0 << 7) + (ks ? kx1 : kx0));     \
    bfr[1][ks] = *(const bf16x8*)((HB) + (rb1 << 7) + (ks ? kx1 : kx0));     \
    bfr[2][ks] = *(const bf16x8*)((HB) + (rb2 << 7) + (ks ? kx1 : kx0));     \
    bfr[3][ks] = *(const bf16x8*)((HB) + (rb3 << 7) + (ks ? kx1 : kx0));     \
  }

#define MMAC(QM, QN, AF)                                                     \
  _Pragma("unroll") for (int ks = 0; ks < 2; ks++)                           \
  _Pragma("unroll") for (int mi = 0; mi < 2; mi++)                           \
  _Pragma("unroll") for (int ni = 0; ni < 4; ni++)                           \
      acc[QM][QN][mi][ni] = __builtin_amdgcn_mfma_f32_16x16x32_bf16(         \
          AF[mi][ks], bfr[ni][ks], acc[QM][QN][mi][ni], 0, 0, 0);

// stage one 128x64 half-tile: 2 gload_lds/thread, linear LDS dest,
// inverse-swizzled global k-offset (kelem) so swizzled reads see logical data
#define STAGE(GP, ROW0, KT, LB)                                              \
  _Pragma("unroll") for (int i_ = 0; i_ < 2; i_++) {                         \
    ll16((GP) + (size_t)((ROW0) + (i_ * 8 + w) * 8 + l8) * D_MODEL +         \
             (KT) * 64 + kelem,                                              \
         (bf16*)((LB) + (i_ * 8 + w) * 1024));                               \
  }

#define PHASE_SYNC_PRE()                                                     \
  __builtin_amdgcn_s_barrier();                                              \
  asm volatile("s_waitcnt lgkmcnt(0)" ::: "memory");                         \
  __builtin_amdgcn_sched_barrier(0);                                         \
  __builtin_amdgcn_s_setprio(1);

#define PHASE_SYNC_POST()                                                    \
  __builtin_amdgcn_s_setprio(0);                                             \
  __builtin_amdgcn_s_barrier();

template <typename TC, int MODE, int NBN>
__global__ __launch_bounds__(512, 2)
void gemm8p(const bf16* __restrict__ A, const bf16* __restrict__ W,
            TC* __restrict__ C, bf16* __restrict__ Qo, bf16* __restrict__ Ko,
            bf16* __restrict__ Vo, const int* __restrict__ pos_ids) {
  __shared__ __align__(16) char smem[131072];

  const int tid  = threadIdx.x;
  const int lane = tid & 63;
  const int w    = tid >> 6;           // 0..7
  const int quad = lane >> 4, l15 = lane & 15;
  const int wr   = w >> 1;             // 0..3: 32-row strip in quadrant
  const int wc   = w & 1;              // 0..1: col pick
  const int l8   = lane >> 3, l7 = lane & 7;
  const int kelem = 8 * (l7 ^ l8);     // inverse-swizzle of global source

  // XCD-bijective swizzle (grid % 8 == 0 for both uses)
  const int nwg = 16 * NBN;
  const int bid = blockIdx.x;
  const int lin = (bid & 7) * (nwg >> 3) + (bid >> 3);
  const int by = lin / NBN, bx = lin % NBN;
  const int mBase = by << 8, nBase = bx << 8;

  // read-side swizzled k offsets: q = (row<<7) + ((ks*64 + quad*16) ^ ((row&7)<<4))
  const int kx0 = (quad * 16) ^ ((l15 & 7) << 4);
  const int kx1 = kx0 ^ 64;
  const int rowA = wr * 32 + l15;
  const int rb0 = wc * 32 + l15, rb1 = rb0 + 16, rb2 = rb0 + 64, rb3 = rb0 + 80;

  f32x4 acc[2][2][2][4];
#pragma unroll
  for (int a = 0; a < 2; a++)
#pragma unroll
    for (int b = 0; b < 2; b++)
#pragma unroll
      for (int c = 0; c < 2; c++)
#pragma unroll
        for (int d = 0; d < 4; d++) acc[a][b][c][d] = 0.0f;

  bf16x8 afA[2][2], afB[2][2], bfr[4][2];

  // prologue: tile0 all 4 halves + tile1's same-slot halves (B h0, A h1)
  {
    char* s = smem;
    STAGE(A, mBase,       0, s + 0);              // A h0 t0
    STAGE(A, mBase + 128, 0, s + 16384);          // A h1 t0
    STAGE(W, nBase,       0, s + 32768);          // B h0 t0
    STAGE(W, nBase + 128, 0, s + 49152);          // B h1 t0
    STAGE(W, nBase,       1, s + 65536 + 32768);  // B h0 t1
    STAGE(A, mBase + 128, 1, s + 65536 + 16384);  // A h1 t1
  }
  asm volatile("s_waitcnt vmcnt(4)" ::: "memory");  // tile0 fully arrived
  __builtin_amdgcn_s_barrier();

  for (int t = 0; t < NT_TILES; ++t) {
    const int buf = t & 1;
    char* const A0  = smem + buf * 65536;
    char* const A1h = A0 + 16384;
    char* const B0  = A0 + 32768;
    char* const B1h = B0 + 16384;
    char* const oA0 = smem + (buf ^ 1) * 65536;
    char* const oB1 = oA0 + 32768 + 16384;

    // ---- P0: quadrant (0,0); stage A h0 (t+1) -> other buf ----
    LOADA(A0, afA);
    LOADB(B0);
    if (t + 1 < NT_TILES) STAGE(A, mBase, t + 1, oA0);
    PHASE_SYNC_PRE();
    MMAC(0, 0, afA);
    PHASE_SYNC_POST();

    // ---- P1: quadrant (1,0); stage B h1 (t+1) -> other buf ----
    LOADA(A1h, afB);
    if (t + 1 < NT_TILES) STAGE(W, nBase + 128, t + 1, oB1);
    PHASE_SYNC_PRE();
    MMAC(1, 0, afB);
    PHASE_SYNC_POST();

    // ---- P2: quadrant (1,1); stage B h0 (t+2) -> SAME buf (B h0 dead) ----
    LOADB(B1h);
    if (t + 2 < NT_TILES) STAGE(W, nBase, t + 2, B0);
    PHASE_SYNC_PRE();
    MMAC(1, 1, afB);
    PHASE_SYNC_POST();

    // ---- P3: quadrant (0,1), afA reused (no ds_read); stage A h1 (t+2) ----
    if (t + 2 < NT_TILES) STAGE(A, mBase + 128, t + 2, A1h);
    __builtin_amdgcn_s_barrier();
    asm volatile("s_waitcnt lgkmcnt(0)" ::: "memory");
    __builtin_amdgcn_sched_barrier(0);
    __builtin_amdgcn_s_setprio(1);
    MMAC(0, 1, afA);
    __builtin_amdgcn_s_setprio(0);
    if (t + 2 < NT_TILES)
      asm volatile("s_waitcnt vmcnt(4)" ::: "memory");  // tile t+1 complete
    else
      asm volatile("s_waitcnt vmcnt(0)" ::: "memory");  // epilogue drain
    __builtin_amdgcn_s_barrier();
  }

  // C/D layout (verified): col = lane&15, row = quad*4 + reg
  // m = mBase + qm*128 + wr*32 + mi*16 + quad*4 + r
  // n = nBase + qn*128 + wc*32 + (ni&1)*16 + (ni>>1)*64 + l15
  if (MODE == 0) {
#pragma unroll
    for (int qm = 0; qm < 2; qm++)
#pragma unroll
      for (int qn = 0; qn < 2; qn++)
#pragma unroll
        for (int mi = 0; mi < 2; mi++)
#pragma unroll
          for (int ni = 0; ni < 4; ni++) {
            int n = nBase + qn * 128 + wc * 32 + (ni & 1) * 16 + (ni >> 1) * 64 + l15;
            int mb = mBase + qm * 128 + wr * 32 + mi * 16 + quad * 4;
            TC* cp = C + (size_t)mb * D_MODEL + n;
#pragma unroll
            for (int r = 0; r < 4; r++) cp[(size_t)r * D_MODEL] = (TC)acc[qm][qn][mi][ni][r];
          }
  } else {
    const int matrix = nBase >> 11;  // 0=Q 1=K 2=V
    const int nb     = nBase & 2047; // within-matrix col base (head-aligned)
    if (matrix == 2) {
#pragma unroll
      for (int qm = 0; qm < 2; qm++)
#pragma unroll
        for (int qn = 0; qn < 2; qn++) {
          const int h = (nb >> 7) + qn;
#pragma unroll
          for (int mi = 0; mi < 2; mi++)
#pragma unroll
            for (int ni = 0; ni < 4; ni++) {
              const int hd = wc * 32 + (ni & 1) * 16 + (ni >> 1) * 64 + l15;
#pragma unroll
              for (int r = 0; r < 4; r++) {
                int m = mBase + qm * 128 + wr * 32 + mi * 16 + quad * 4 + r;
                int b = m >> 11, s2 = m & 2047;
                Vo[((size_t)((b * NH + h) * HEAD_DIM + hd)) * SEQ + s2] =
                    (bf16)acc[qm][qn][mi][ni][r];
              }
            }
        }
    } else {
      bf16* Out = (matrix == 0) ? Qo : Ko;
      float invf[2];
#pragma unroll
      for (int ni = 0; ni < 2; ni++)
        invf[ni] = __expf(-(float)(wc * 32 + ni * 16 + l15) *
                          (9.210340371976184f / 64.0f));
#pragma unroll
      for (int qm = 0; qm < 2; qm++)
#pragma unroll
        for (int mi = 0; mi < 2; mi++)
#pragma unroll
          for (int r = 0; r < 4; r++) {
            int m = mBase + qm * 128 + wr * 32 + mi * 16 + quad * 4 + r;
            float pos = (float)pos_ids[m];
#pragma unroll
            for (int qn = 0; qn < 2; qn++) {
              bf16* op = Out + (size_t)m * D_MODEL + nb + qn * 128 + wc * 32 + l15;
#pragma unroll
              for (int ni = 0; ni < 2; ni++) {
                float sn, cs;
                __sincosf(pos * invf[ni], &sn, &cs);
                float q0 = acc[qm][qn][mi][ni][r];
                float q1 = acc[qm][qn][mi][ni + 2][r];
                op[ni * 16]      = (bf16)(q0 * cs - q1 * sn);
                op[ni * 16 + 64] = (bf16)(q1 * cs + q0 * sn);
              }
            }
          }
    }
  }
}

// ---------------------------------------------------------------------------
// Final projection: BM=128 x BN=256 -> 32x8 = 256 blocks = EXACTLY one full
// round (R1's 256^2 grid was 128 blocks = half the GPU idle). 48KB/tile
// allows TRIPLE-buffered LDS (144 KiB): prefetch depth 2 tiles, counted
// vmcnt(6) that never drains to 0 in the main loop. 2 phases x 16 MFMA per
// K-tile; 8 waves as 2M x 4N, per-wave 64x64 output. Same verified XOR
// swizzle (linear gload_lds dest + inverse-swizzled global source).
// ---------------------------------------------------------------------------
__global__ __launch_bounds__(512, 2)
void gemm_proj(const bf16* __restrict__ A, const bf16* __restrict__ W,
               float* __restrict__ C) {
  __shared__ __align__(16) char smem[147456];  // 3 x 49152 (A 16K + B 32K)

  const int tid  = threadIdx.x;
  const int lane = tid & 63;
  const int w    = tid >> 6;
  const int quad = lane >> 4, l15 = lane & 15;
  const int l8   = lane >> 3, l7 = lane & 7;
  const int kelem = 8 * (l7 ^ l8);
  const int wr = w >> 2, wc = w & 3;

  const int bid = blockIdx.x;                 // 256 blocks
  const int lin = (bid & 7) * 32 + (bid >> 3);  // XCD-bijective
  const int by = lin >> 3, bx = lin & 7;
  const int mBase = by << 7, nBase = bx << 8;

  const int kx0 = (quad * 16) ^ ((l15 & 7) << 4);
  const int kx1 = kx0 ^ 64;
  const int arow = wr * 64 + l15;   // + mi*16 ; region [0,16384)
  const int brow = wc * 64 + l15;   // + ni*16 ; region [16384,49152)

  f32x4 acc[4][4];
#pragma unroll
  for (int i = 0; i < 4; i++)
#pragma unroll
    for (int j = 0; j < 4; j++) acc[i][j] = 0.0f;

  bf16x8 af[4], bfr[4];

  // stage one 64-row x 64-k unit (8KB): lane covers row w*8+l8, inv-swz k
#define ST1(GP, ROW0, KT, LB)                                                \
  ll16((GP) + (size_t)((ROW0) + w * 8 + l8) * D_MODEL + (KT) * 64 + kelem,   \
       (bf16*)((LB) + w * 1024));

  // prologue: tiles 0 and 1 fully staged (12 units)
  {
    char* s0 = smem;
    char* s1 = smem + 49152;
    ST1(A, mBase,       0, s0 + 0);
    ST1(A, mBase + 64,  0, s0 + 8192);
    ST1(W, nBase,       0, s0 + 16384);
    ST1(W, nBase + 64,  0, s0 + 24576);
    ST1(W, nBase + 128, 0, s0 + 32768);
    ST1(W, nBase + 192, 0, s0 + 40960);
    ST1(A, mBase,       1, s1 + 0);
    ST1(A, mBase + 64,  1, s1 + 8192);
    ST1(W, nBase,       1, s1 + 16384);
    ST1(W, nBase + 64,  1, s1 + 24576);
    ST1(W, nBase + 128, 1, s1 + 32768);
    ST1(W, nBase + 192, 1, s1 + 40960);
  }
  asm volatile("s_waitcnt vmcnt(6)" ::: "memory");  // tile0 arrived
  __builtin_amdgcn_s_barrier();

  int buf = 0;
  for (int t = 0; t < NT_TILES; ++t) {
    char* const Sb = smem + buf * 49152;
    const int  pb  = (buf + 2 >= 3) ? buf - 1 : buf + 2;
    char* const Pb = smem + pb * 49152;
    const bool pf  = (t + 2 < NT_TILES);

    // ---- P0 (k 0..31); stage first 3 units of t+2 ----
#pragma unroll
    for (int mi = 0; mi < 4; mi++)
      af[mi] = *(const bf16x8*)(Sb + ((arow + mi * 16) << 7) + kx0);
#pragma unroll
    for (int ni = 0; ni < 4; ni++)
      bfr[ni] = *(const bf16x8*)(Sb + 16384 + ((brow + ni * 16) << 7) + kx0);
    if (pf) {
      ST1(A, mBase,      t + 2, Pb + 0);
      ST1(A, mBase + 64, t + 2, Pb + 8192);
      ST1(W, nBase,      t + 2, Pb + 16384);
    }
    PHASE_SYNC_PRE();
#pragma unroll
    for (int mi = 0; mi < 4; mi++)
#pragma unroll
      for (int ni = 0; ni < 4; ni++)
        acc[mi][ni] = __builtin_amdgcn_mfma_f32_16x16x32_bf16(
            af[mi], bfr[ni], acc[mi][ni], 0, 0, 0);
    PHASE_SYNC_POST();

    // ---- P1 (k 32..63); stage last 3 units of t+2 ----
#pragma unroll
    for (int mi = 0; mi < 4; mi++)
      af[mi] = *(const bf16x8*)(Sb + ((arow + mi * 16) << 7) + kx1);
#pragma unroll
    for (int ni = 0; ni < 4; ni++)
      bfr[ni] = *(const bf16x8*)(Sb + 16384 + ((brow + ni * 16) << 7) + kx1);
    if (pf) {
      ST1(W, nBase + 64,  t + 2, Pb + 24576);
      ST1(W, nBase + 128, t + 2, Pb + 32768);
      ST1(W, nBase + 192, t + 2, Pb + 40960);
    }
    __builtin_amdgcn_s_barrier();
    asm volatile("s_waitcnt lgkmcnt(0)" ::: "memory");
    __builtin_amdgcn_sched_barrier(0);
    __builtin_amdgcn_s_setprio(1);
#pragma unroll
    for (int mi = 0; mi < 4; mi++)
#pragma unroll
      for (int ni = 0; ni < 4; ni++)
        acc[mi][ni] = __builtin_amdgcn_mfma_f32_16x16x32_bf16(
            af[mi], bfr[ni], acc[mi][ni], 0, 0, 0);
    __builtin_amdgcn_s_setprio(0);
    if (pf)
      asm volatile("s_waitcnt vmcnt(6)" ::: "memory");  // tile t+1 complete
    else
      asm volatile("s_waitcnt vmcnt(0)" ::: "memory");  // drain tail
    __builtin_amdgcn_s_barrier();

    buf = (buf == 2) ? 0 : buf + 1;
  }
#undef ST1

  // epilogue: m = mBase + wr*64 + mi*16 + quad*4 + r; n = nBase + wc*64 + ni*16 + l15
#pragma unroll
  for (int mi = 0; mi < 4; mi++) {
    const int m = mBase + wr * 64 + mi * 16 + quad * 4;
#pragma unroll
    for (int ni = 0; ni < 4; ni++) {
      const int n = nBase + wc * 64 + ni * 16 + l15;
      float* cp = C + (size_t)m * D_MODEL + n;
#pragma unroll
      for (int r = 0; r < 4; r++) cp[(size_t)r * D_MODEL] = acc[mi][ni][r];
    }
  }
}

// ---------------------------------------------------------------------------
// MFMA flash attention, causal (unchanged this round). One 64-row q-subtile
// per block (4 waves x 16 rows); grid (bh=32, 32) with s = 31 - blockIdx.y.
// ---------------------------------------------------------------------------
__global__ __launch_bounds__(256, 3)
void attn_mfma(const bf16* __restrict__ Q, const bf16* __restrict__ K,
               const bf16* __restrict__ Vt, bf16* __restrict__ O) {
  __shared__ __align__(16) bf16 K_lds[64 * 136];   // [t][hd], pad 128->136
  __shared__ __align__(16) bf16 V_lds[128 * 72];   // [d][t],  pad 64->72
  __shared__ __align__(16) bf16 P_lds[64 * 72];    // wave-local 16 rows each

  const int tid  = threadIdx.x;
  const int lane = tid & 63;
  const int w    = tid >> 6;
  const int quad = lane >> 4, l15 = lane & 15;
  const int s    = 31 - blockIdx.y;   // subtile index, heavy first
  const int bh   = blockIdx.x;        // b*NH + h
  const size_t qkBase = (size_t)(bh >> 4) * SEQ * D_MODEL + (size_t)(bh & 15) * HEAD_DIM;
  const size_t vBase  = (size_t)bh * HEAD_DIM * SEQ;

  const int qbase = s * 64 + w * 16;  // wave's 16 q-rows

  bf16x8 qa[4];
#pragma unroll
  for (int kk = 0; kk < 4; kk++)
    qa[kk] = *(const bf16x8*)(Q + qkBase + (size_t)(qbase + l15) * D_MODEL + kk * 32 + quad * 8);

  bf16x8 ones;
#pragma unroll
  for (int i = 0; i < 8; i++) ones[i] = (bf16)1.0f;

  f32x4 oacc[8], ls;
#pragma unroll
  for (int ni = 0; ni < 8; ni++) oacc[ni] = 0.0f;
  ls = 0.0f;

  const int ntiles = s + 1;

  bf16x8 kr[4], vr[4];
  auto loadKV = [&](int t0) {
#pragma unroll
    for (int i = 0; i < 4; i++) {
      int c = tid + 256 * i;
      kr[i] = *(const bf16x8*)(K + qkBase + (size_t)(t0 + (c >> 4)) * D_MODEL + (c & 15) * 8);
    }
#pragma unroll
    for (int i = 0; i < 4; i++) {
      int c = tid + 256 * i;
      vr[i] = *(const bf16x8*)(Vt + vBase + (size_t)(c >> 3) * SEQ + t0 + (c & 7) * 8);
    }
  };
  loadKV(0);

  const int prow = w * 16;  // wave-local P rows

  for (int tt = 0; tt < ntiles; tt++) {
    const int t0 = tt * 64;
    __syncthreads();
#pragma unroll
    for (int i = 0; i < 4; i++) {
      int c = tid + 256 * i;
      *(bf16x8*)&K_lds[(c >> 4) * 136 + (c & 15) * 8] = kr[i];
    }
#pragma unroll
    for (int i = 0; i < 4; i++) {
      int c = tid + 256 * i;
      *(bf16x8*)&V_lds[(c >> 3) * 72 + (c & 7) * 8] = vr[i];
    }
    __syncthreads();
    if (tt + 1 < ntiles) loadKV(t0 + 64);

    // --- S = Q K^T ---
    f32x4 sacc[4];
#pragma unroll
    for (int ni = 0; ni < 4; ni++) sacc[ni] = 0.0f;
#pragma unroll
    for (int kk = 0; kk < 4; kk++) {
#pragma unroll
      for (int ni = 0; ni < 4; ni++) {
        bf16x8 kf = *(const bf16x8*)&K_lds[(ni * 16 + l15) * 136 + kk * 32 + quad * 8];
        sacc[ni] = __builtin_amdgcn_mfma_f32_16x16x32_bf16(qa[kk], kf, sacc[ni], 0, 0, 0);
      }
    }

    // --- exp (+mask on diagonal tile only) -> P_lds ---
    if (tt == s) {
#pragma unroll
      for (int r = 0; r < 4; r++) {
        int qrow = qbase + quad * 4 + r;
#pragma unroll
        for (int ni = 0; ni < 4; ni++) {
          int tcol = t0 + ni * 16 + l15;
          float pv = (tcol <= qrow) ? __expf(fminf(sacc[ni][r] * SM_SCALE, 30.0f)) : 0.0f;
          P_lds[(prow + quad * 4 + r) * 72 + ni * 16 + l15] = (bf16)pv;
        }
      }
    } else {
#pragma unroll
      for (int r = 0; r < 4; r++)
#pragma unroll
        for (int ni = 0; ni < 4; ni++)
          P_lds[(prow + quad * 4 + r) * 72 + ni * 16 + l15] =
              (bf16)__expf(fminf(sacc[ni][r] * SM_SCALE, 30.0f));
    }

    // --- O += P V; row-sum via ones-vector MFMA ---
#pragma unroll
    for (int kk2 = 0; kk2 < 2; kk2++) {
      bf16x8 pf = *(const bf16x8*)&P_lds[(prow + l15) * 72 + kk2 * 32 + quad * 8];
#pragma unroll
      for (int ni = 0; ni < 8; ni++) {
        bf16x8 vf = *(const bf16x8*)&V_lds[(ni * 16 + l15) * 72 + kk2 * 32 + quad * 8];
        oacc[ni] = __builtin_amdgcn_mfma_f32_16x16x32_bf16(pf, vf, oacc[ni], 0, 0, 0);
      }
      ls = __builtin_amdgcn_mfma_f32_16x16x32_bf16(pf, ones, ls, 0, 0, 0);
    }
  }

  // epilogue
#pragma unroll
  for (int r = 0; r < 4; r++) {
    float inv = 1.0f / ls[r];
    bf16* op = O + qkBase + (size_t)(qbase + quad * 4 + r) * D_MODEL;
#pragma unroll
    for (int ni = 0; ni < 8; ni++)
      op[ni * 16 + l15] = (bf16)(oacc[ni][r] * inv);
  }
}

extern "C" void kernel_launch(void* const* d_in, const int* in_sizes, int n_in,
                              void* d_out, int out_size, void* d_ws, size_t ws_size,
                              hipStream_t stream) {
  const float* hidden = (const float*)d_in[0];
  // d_in[1] = attention_mask (causal -1e9): applied analytically in attn_mfma
  const int* pos = (const int*)d_in[2];
  const float* Wq = (const float*)d_in[3];
  const float* Wk = (const float*)d_in[4];
  const float* Wv = (const float*)d_in[5];
  const float* Wo = (const float*)d_in[6];
  float* out = (float*)d_out;

  const size_t TENS = (size_t)NBATCH * SEQ * D_MODEL;  // 8,388,608
  bf16* Qb = (bf16*)d_ws;
  bf16* Kb = Qb + TENS;
  bf16* Vt = Kb + TENS;      // [B,H,HD,S]
  bf16* AO = Vt + TENS;      // attention out [B,S,D]
  bf16* Hb = AO + TENS;      // bf16 hidden
  bf16* Wb = Hb + TENS;      // [Wq;Wk;Wv;Wo] bf16, fused N=6144 rows

  cvt_hidden<<<dim3(TENS / 2048), dim3(256), 0, stream>>>(hidden, Hb);
  cvt_weights<<<dim3(WSEG / 2048, 4), dim3(256), 0, stream>>>(Wq, Wk, Wv, Wo, Wb);

  // fused QKV projection + RoPE + V-transpose: M=4096, N=6144 -> 16x24 blocks
  gemm8p<bf16, 1, 24><<<dim3(384), dim3(512), 0, stream>>>(
      Hb, Wb, (bf16*)nullptr, Qb, Kb, Vt, pos);

  attn_mfma<<<dim3(NBATCH * NH, 32), dim3(256), 0, stream>>>(Qb, Kb, Vt, AO);

  // final projection: M=4096, N=2048 -> 32x8 = 256 blocks, one full round
  gemm_proj<<<dim3(256), dim3(512), 0, stream>>>(
      AO, Wb + 3 * (size_t)WSEG, out);
}